// Round 16
// baseline (767.813 us; speedup 1.0000x reference)
//
#include <hip/hip_runtime.h>
#include <hip/hip_bf16.h>

#define NN   30000
#define EE   960000
#define IND  2048
#define NEMB 64
#define NH1  32
#define NH2  16
#define NET  64
#define NB   16
#define NBLKC 512

typedef __bf16 bf8 __attribute__((ext_vector_type(8)));
typedef __bf16 bf4 __attribute__((ext_vector_type(4)));
typedef __bf16 bf2 __attribute__((ext_vector_type(2)));
typedef float  f4  __attribute__((ext_vector_type(4)));

#define AS3 __attribute__((address_space(3)))
#define AS1 __attribute__((address_space(1)))

__device__ __forceinline__ void gll16(const void* g, void* l) {
    __builtin_amdgcn_global_load_lds((const AS1 unsigned int*)g,
                                     (AS3 unsigned int*)l, 16, 0, 0);
}

__device__ __forceinline__ bf8 bf8_zero() {
    bf8 z;
#pragma unroll
    for (int i = 0; i < 8; i++) z[i] = (__bf16)0.0f;
    return z;
}

// r15-proven grid barrier: one RMW arrive per block, LOAD-only spin.
__device__ __forceinline__ void gridbar(int* bar, int target) {
    __syncthreads();
    if (threadIdx.x == 0) {
        __threadfence();
        if (atomicAdd(&bar[0], 1) == NBLKC - 1) {
            bar[0] = 0;
            __threadfence();
            atomicAdd(&bar[1], 1);
        }
        while (__hip_atomic_load(&bar[1], __ATOMIC_ACQUIRE,
                                 __HIP_MEMORY_SCOPE_AGENT) < target)
            __builtin_amdgcn_s_sleep(32);
        __threadfence();
    }
    __syncthreads();
}

// ================= K1: prep (grid-stride) -> bar -> gemm+init1 (grid-stride) ======
__global__ __launch_bounds__(256, 2) void k_prep_gemm(
        const float* __restrict__ embed, const float* __restrict__ basis1,
        const float* __restrict__ att1, const float* __restrict__ basis2,
        const float* __restrict__ att2, const float* __restrict__ x,
        const float* __restrict__ xnorm, const float* __restrict__ root1,
        const float* __restrict__ bias1,
        __bf16* __restrict__ embT, __bf16* __restrict__ W1T, __bf16* __restrict__ W2T,
        __bf16* __restrict__ h0b, float* __restrict__ out1, int* __restrict__ bar) {
    __shared__ __align__(16) float  As[2][32 * 128];    // 32 KB
    __shared__ __align__(16) __bf16 Bs[2][64 * 128];    // 32 KB
    int t = threadIdx.x;
    int wv = t >> 6, lane = t & 63;
    int l15 = lane & 15, kg = lane >> 4;

    // ---- phase A: prep (virtual blocks 0..639) ----
    for (int vb = blockIdx.x; vb < 640; vb += NBLKC) {
        if (vb < 512) {
            int idx = vb * 256 + t;                 // embT[n][k] = embed[k][n]
            int n = idx >> 11, k = idx & 2047;
            embT[idx] = (__bf16)embed[k * NEMB + n];
        } else if (vb < 576) {
            int r = vb - 512;
            float* a = (float*)&As[0][0];
            if (t < NB) a[t] = att1[r * NB + t];
            __syncthreads();
            for (int idx = t; idx < NH1 * NEMB; idx += 256) {
                int o = idx >> 6, i = idx & 63;
                float acc = 0.f;
#pragma unroll
                for (int bb = 0; bb < NB; bb++) acc += a[bb] * basis1[(bb * NEMB + i) * NH1 + o];
                W1T[r * (NH1 * NEMB) + idx] = (__bf16)acc;
            }
            __syncthreads();
        } else {
            int r = vb - 576;
            float* a = (float*)&As[0][0];
            if (t < NB) a[t] = att2[r * NB + t];
            __syncthreads();
            for (int idx = t; idx < NH2 * NH1; idx += 256) {
                int o = idx >> 5, i = idx & 31;
                float acc = 0.f;
#pragma unroll
                for (int bb = 0; bb < NB; bb++) acc += a[bb] * basis2[(bb * NH1 + i) * NH2 + o];
                W2T[r * (NH2 * NH1) + idx] = (__bf16)acc;
            }
            __syncthreads();
        }
    }
    gridbar(bar, 1);

    // ---- phase B: r10 gemm + fused init1, grid-stride over 938 tiles ----
    int half = lane >> 5;
    int bslot = lane & 31;
    int q16 = lane >> 4;
    int slot16 = lane & 15;
    int n = wv * 16 + l15;
    int nswz = (n & 7) << 4;
    int aswz = (l15 & 7) << 4;

    for (int vt = blockIdx.x; vt < 938; vt += NBLKC) {
        int rowbase = vt * 32;
        f4 acc0 = (f4)0.0f, acc1 = (f4)0.0f;

        auto STAGE = [&](int c, int buf) {
#pragma unroll
            for (int i = 0; i < 4; i++) {               // A: 4 gll
                int rp = wv * 4 + i;
                int row = rp * 2 + half;
                int grow = rowbase + row;
                if (grow >= NN) grow = NN - 1;
                const char* g = (const char*)x + (size_t)grow * (IND * 4) + c * 512
                              + ((bslot * 16) ^ ((row & 7) << 4));
                gll16(g, (char*)&As[buf][0] + rp * 1024);
            }
#pragma unroll
            for (int i = 0; i < 4; i++) {               // B: 4 gll
                int rp = wv * 4 + i;
                int row = rp * 4 + q16;
                const char* g = (const char*)embT + (size_t)row * (IND * 2) + c * 256
                              + ((slot16 * 16) ^ ((row & 7) << 4));
                gll16(g, (char*)&Bs[buf][0] + rp * 1024);
            }
        };

        STAGE(0, 0);
        for (int c = 0; c < 16; c++) {
            int buf = c & 1;
            if (c < 15) {
                STAGE(c + 1, buf ^ 1);
                asm volatile("s_waitcnt vmcnt(8)" ::: "memory");
            } else {
                asm volatile("s_waitcnt vmcnt(0)" ::: "memory");
            }
            __builtin_amdgcn_s_barrier();
            __builtin_amdgcn_sched_barrier(0);
            const char* bsrow  = (const char*)&Bs[buf][0] + n * 256;
            const char* asrow0 = (const char*)&As[buf][0] + l15 * 512;
            const char* asrow1 = (const char*)&As[buf][0] + (l15 + 16) * 512;
#pragma unroll
            for (int kk = 0; kk < 4; kk++) {
                int aoff = ((kk * 128 + kg * 32) ^ aswz);
                float4 lo0 = *(const float4*)(asrow0 + aoff);
                float4 hi0 = *(const float4*)(asrow0 + (aoff ^ 16));
                float4 lo1 = *(const float4*)(asrow1 + aoff);
                float4 hi1 = *(const float4*)(asrow1 + (aoff ^ 16));
                bf8 b = *(const bf8*)(bsrow + ((kk * 64 + kg * 16) ^ nswz));
                bf8 a0, a1;
                a0[0]=(__bf16)lo0.x; a0[1]=(__bf16)lo0.y; a0[2]=(__bf16)lo0.z; a0[3]=(__bf16)lo0.w;
                a0[4]=(__bf16)hi0.x; a0[5]=(__bf16)hi0.y; a0[6]=(__bf16)hi0.z; a0[7]=(__bf16)hi0.w;
                a1[0]=(__bf16)lo1.x; a1[1]=(__bf16)lo1.y; a1[2]=(__bf16)lo1.z; a1[3]=(__bf16)lo1.w;
                a1[4]=(__bf16)hi1.x; a1[5]=(__bf16)hi1.y; a1[6]=(__bf16)hi1.z; a1[7]=(__bf16)hi1.w;
                acc0 = __builtin_amdgcn_mfma_f32_16x16x32_bf16(a0, b, acc0, 0, 0, 0);
                acc1 = __builtin_amdgcn_mfma_f32_16x16x32_bf16(a1, b, acc1, 0, 0, 0);
            }
            __builtin_amdgcn_sched_barrier(0);
            __builtin_amdgcn_s_barrier();
        }
        // epilogue: h0 -> global + LDS, then fused init1
        __bf16* h0s = (__bf16*)&As[0][0];
#pragma unroll
        for (int j = 0; j < 4; j++) {
            int lr0 = kg * 4 + j, lr1 = lr0 + 16;
            int r0 = rowbase + lr0, r1 = rowbase + lr1;
            float v0 = 0.f, v1 = 0.f;
            if (r0 < NN) v0 = acc0[j] / xnorm[r0];
            if (r1 < NN) v1 = acc1[j] / xnorm[r1];
            __bf16 b0 = (__bf16)v0, b1 = (__bf16)v1;
            if (r0 < NN) h0b[(size_t)r0 * NEMB + n] = b0;
            if (r1 < NN) h0b[(size_t)r1 * NEMB + n] = b1;
            h0s[lr0 * NEMB + n] = b0;
            h0s[lr1 * NEMB + n] = b1;
        }
        __syncthreads();
        {
            int row = t >> 3, c0 = (t & 7) * 4;
            int grow = rowbase + row;
            if (grow < NN) {
                const __bf16* hr = h0s + row * NEMB;
                float4 acc = *(const float4*)(bias1 + c0);
#pragma unroll
                for (int k = 0; k < NEMB; k++) {
                    float a = (float)hr[k];
                    float4 w = *(const float4*)(root1 + k * NH1 + c0);
                    acc.x += a * w.x; acc.y += a * w.y;
                    acc.z += a * w.z; acc.w += a * w.w;
                }
                *(float4*)(out1 + (size_t)grow * NH1 + c0) = acc;
            }
        }
        __syncthreads();                      // protect smem reuse by next tile
    }
}

// ================= K2: edge layer 1 (r10 verbatim, 7500 blocks) =================
__global__ __launch_bounds__(256) void k_edge1(const int* __restrict__ ei,
                                               const int* __restrict__ et,
                                               const __bf16* __restrict__ h0b,
                                               const __bf16* __restrict__ W1T,
                                               float* __restrict__ out1) {
    int wave = threadIdx.x >> 6, lane = threadIdx.x & 63;
    int l15 = lane & 15, kg = lane >> 4;
    int wid = blockIdx.x * 4 + wave;
    int er0 = wid * 32 + l15, er1 = er0 + 16;
    int et0v = et[er0],  et1v = et[er1];
    int src0 = ei[er0],  src1 = ei[er1];
    int dst0 = ei[EE + er0], dst1 = ei[EE + er1];
    const __bf16* hp0 = h0b + (size_t)src0 * NEMB + kg * 8;
    const __bf16* hp1 = h0b + (size_t)src1 * NEMB + kg * 8;
    bf8 a00 = *(const bf8*)hp0;
    bf8 a01 = *(const bf8*)(hp0 + 32);
    bf8 a10 = *(const bf8*)hp1;
    bf8 a11 = *(const bf8*)(hp1 + 32);
    bf8 zero = bf8_zero();
#pragma unroll
    for (int b = 0; b < 2; b++) {
        int my_et = b ? et1v : et0v;
        int my_dst = b ? dst1 : dst0;
        bf8 a0 = b ? a10 : a00;
        bf8 a1 = b ? a11 : a01;
        f4 c0 = (f4)0.0f, c1 = (f4)0.0f;
        int pos = 0;
        while (pos < 16) {
            int r = __shfl(my_et, pos);
            unsigned long long bl = __ballot(my_et == r);
            unsigned m16 = (unsigned)(bl & 0xFFFFull);
            int run = __builtin_ctz(~(m16 >> pos));
            int end = pos + run;
            const __bf16* wb = W1T + (size_t)r * (NH1 * NEMB) + (size_t)l15 * NEMB + kg * 8;
            bf8 b00 = *(const bf8*)(wb);
            bf8 b01 = *(const bf8*)(wb + 32);
            bf8 b10 = *(const bf8*)(wb + 16 * NEMB);
            bf8 b11 = *(const bf8*)(wb + 16 * NEMB + 32);
            bool use = (l15 >= pos) && (l15 < end);
            bf8 ua0 = use ? a0 : zero;
            bf8 ua1 = use ? a1 : zero;
            c0 = __builtin_amdgcn_mfma_f32_16x16x32_bf16(ua0, b00, c0, 0, 0, 0);
            c0 = __builtin_amdgcn_mfma_f32_16x16x32_bf16(ua1, b01, c0, 0, 0, 0);
            c1 = __builtin_amdgcn_mfma_f32_16x16x32_bf16(ua0, b10, c1, 0, 0, 0);
            c1 = __builtin_amdgcn_mfma_f32_16x16x32_bf16(ua1, b11, c1, 0, 0, 0);
            pos = end;
        }
#pragma unroll
        for (int j = 0; j < 4; j++) {
            int eidx = kg * 4 + j;
            int dst = __shfl(my_dst, eidx);
            atomicAdd(out1 + (size_t)dst * NH1 + l15,      c0[j]);
            atomicAdd(out1 + (size_t)dst * NH1 + 16 + l15, c1[j]);
        }
    }
}

// ================= K3: mid -> bar -> edge2 -> bar -> relu2 =================
__global__ __launch_bounds__(256, 2) void k_tail(const int* __restrict__ ei,
                                                 const int* __restrict__ et,
                                                 const float* __restrict__ out1,
                                                 const float* __restrict__ root2,
                                                 const float* __restrict__ bias2,
                                                 const __bf16* __restrict__ W2T,
                                                 __bf16* __restrict__ h1b,
                                                 float* __restrict__ out,
                                                 int* __restrict__ bar) {
    int t = threadIdx.x;
    int wv = t >> 6, lane = t & 63;
    int l15 = lane & 15, kg = lane >> 4;

    // ---- mid: relu(out1) -> h1b bf16, out = bias2 + h1 @ root2 ----
    for (int rb = blockIdx.x; rb < 1875; rb += NBLKC) {
        int row = rb * 16 + (t >> 4);
        int col = t & 15;
        const float* orow = out1 + (size_t)row * NH1;
        float h[NH1];
#pragma unroll
        for (int k = 0; k < NH1; k++) h[k] = fmaxf(orow[k], 0.f);
        bf2 hb;
        hb[0] = (__bf16)h[2 * col];
        hb[1] = (__bf16)h[2 * col + 1];
        *(bf2*)(h1b + (size_t)row * NH1 + 2 * col) = hb;
        float acc = bias2[col];
#pragma unroll
        for (int k = 0; k < NH1; k++) acc += h[k] * root2[k * NH2 + col];
        out[(size_t)row * NH2 + col] = acc;
    }
    gridbar(bar, 1);

    // ---- edge2: atomic scatter, 2048 waves x ~15 iters ----
    {
        bf8 zero = bf8_zero();
        for (int wid = blockIdx.x * 4 + wv; wid < NN; wid += NBLKC * 4) {
            int er0 = wid * 32 + l15, er1 = er0 + 16;
            int et0v = et[er0],  et1v = et[er1];
            int src0 = ei[er0],  src1 = ei[er1];
            int dst0 = ei[EE + er0], dst1 = ei[EE + er1];
            bf8 ab0 = *(const bf8*)(h1b + (size_t)src0 * NH1 + kg * 8);
            bf8 ab1 = *(const bf8*)(h1b + (size_t)src1 * NH1 + kg * 8);
#pragma unroll
            for (int s = 0; s < 2; s++) {
                int my_et = s ? et1v : et0v;
                int my_dst = s ? dst1 : dst0;
                bf8 a = s ? ab1 : ab0;
                f4 c = (f4)0.0f;
                int pos = 0;
                while (pos < 16) {
                    int r = __shfl(my_et, pos);
                    unsigned long long bl = __ballot(my_et == r);
                    unsigned m16 = (unsigned)(bl & 0xFFFFull);
                    int run = __builtin_ctz(~(m16 >> pos));
                    int end = pos + run;
                    bf8 bb = *(const bf8*)(W2T + (size_t)r * (NH2 * NH1) + (size_t)l15 * NH1 + kg * 8);
                    bool use = (l15 >= pos) && (l15 < end);
                    c = __builtin_amdgcn_mfma_f32_16x16x32_bf16(use ? a : zero, bb, c, 0, 0, 0);
                    pos = end;
                }
#pragma unroll
                for (int j = 0; j < 4; j++) {
                    int eidx = kg * 4 + j;
                    int dst = __shfl(my_dst, eidx);
                    atomicAdd(out + (size_t)dst * NH2 + l15, c[j]);
                }
            }
        }
    }
    gridbar(bar, 2);

    // ---- relu2 in place ----
    for (int i = blockIdx.x * 256 + t; i < NN * NH2 / 4; i += NBLKC * 256) {
        float4 v = ((float4*)out)[i];
        v.x = fmaxf(v.x, 0.f); v.y = fmaxf(v.y, 0.f);
        v.z = fmaxf(v.z, 0.f); v.w = fmaxf(v.w, 0.f);
        ((float4*)out)[i] = v;
    }
}

// ---------------- launch ----------------
extern "C" void kernel_launch(void* const* d_in, const int* in_sizes, int n_in,
                              void* d_out, int out_size, void* d_ws, size_t ws_size,
                              hipStream_t stream) {
    const float* x      = (const float*)d_in[0];
    const int*   ei     = (const int*)d_in[1];
    const int*   et     = (const int*)d_in[2];
    const float* xnorm  = (const float*)d_in[4];
    const float* embed  = (const float*)d_in[5];
    const float* basis1 = (const float*)d_in[6];
    const float* att1   = (const float*)d_in[7];
    const float* root1  = (const float*)d_in[8];
    const float* bias1  = (const float*)d_in[9];
    const float* basis2 = (const float*)d_in[10];
    const float* att2   = (const float*)d_in[11];
    const float* root2  = (const float*)d_in[12];
    const float* bias2  = (const float*)d_in[13];
    float* out = (float*)d_out;

    char* ws = (char*)d_ws;
    __bf16* embT = (__bf16*)(ws + 0);              //   262,144
    __bf16* W1T  = (__bf16*)(ws + 262144);         //   262,144
    __bf16* W2T  = (__bf16*)(ws + 524288);         //    65,536
    __bf16* h0b  = (__bf16*)(ws + 589824);         // 3,840,000
    float*  out1 = (float*) (ws + 4429824);        // 3,840,000
    __bf16* h1b  = (__bf16*)(ws + 8269824);        // 1,920,000
    int*    bar1 = (int*)   (ws + 10189824);       //        32
    int*    bar2 = (int*)   (ws + 10189856);       //        32  (end ~10.2 MB)

    hipMemsetAsync(bar1, 0, 64, stream);
    k_prep_gemm<<<NBLKC, 256, 0, stream>>>(embed, basis1, att1, basis2, att2, x,
                                           xnorm, root1, bias1,
                                           embT, W1T, W2T, h0b, out1, bar1);
    k_edge1    <<<7500,  256, 0, stream>>>(ei, et, h0b, W1T, out1);
    k_tail     <<<NBLKC, 256, 0, stream>>>(ei, et, out1, root2, bias2, W2T,
                                           h1b, out, bar2);
}

// Round 18
// 229.859 us; speedup vs baseline: 3.3404x; 3.3404x over previous
//
#include <hip/hip_runtime.h>
#include <hip/hip_bf16.h>

#define NN   30000
#define EE   960000
#define IND  2048
#define NEMB 64
#define NH1  32
#define NH2  16
#define NET  64
#define NB   16

typedef __bf16 bf8 __attribute__((ext_vector_type(8)));
typedef __bf16 bf4 __attribute__((ext_vector_type(4)));
typedef __bf16 bf2 __attribute__((ext_vector_type(2)));
typedef float  f4  __attribute__((ext_vector_type(4)));

#define AS3 __attribute__((address_space(3)))
#define AS1 __attribute__((address_space(1)))

__device__ __forceinline__ void gll16(const void* g, void* l) {
    __builtin_amdgcn_global_load_lds((const AS1 unsigned int*)g,
                                     (AS3 unsigned int*)l, 16, 0, 0);
}

__device__ __forceinline__ bf8 bf8_zero() {
    bf8 z;
#pragma unroll
    for (int i = 0; i < 8; i++) z[i] = (__bf16)0.0f;
    return z;
}

// ---------------- prep: embT + W1T + W2T (grid-split, r10 verbatim) ----------------
__global__ __launch_bounds__(256) void k_prep(const float* __restrict__ embed,
                                              const float* __restrict__ basis1,
                                              const float* __restrict__ att1,
                                              const float* __restrict__ basis2,
                                              const float* __restrict__ att2,
                                              __bf16* __restrict__ embT,
                                              __bf16* __restrict__ W1T,
                                              __bf16* __restrict__ W2T) {
    int b = blockIdx.x;
    if (b < 512) {
        int idx = b * 256 + threadIdx.x;        // embT[n][k] = embed[k][n]
        int n = idx >> 11, k = idx & 2047;
        embT[idx] = (__bf16)embed[k * NEMB + n];
    } else if (b < 576) {
        int r = b - 512;
        __shared__ float a[NB];
        if (threadIdx.x < NB) a[threadIdx.x] = att1[r * NB + threadIdx.x];
        __syncthreads();
        for (int idx = threadIdx.x; idx < NH1 * NEMB; idx += 256) {
            int o = idx >> 6, i = idx & 63;
            float acc = 0.f;
#pragma unroll
            for (int bb = 0; bb < NB; bb++) acc += a[bb] * basis1[(bb * NEMB + i) * NH1 + o];
            W1T[r * (NH1 * NEMB) + idx] = (__bf16)acc;
        }
    } else {
        int r = b - 576;
        __shared__ float a[NB];
        if (threadIdx.x < NB) a[threadIdx.x] = att2[r * NB + threadIdx.x];
        __syncthreads();
        for (int idx = threadIdx.x; idx < NH2 * NH1; idx += 256) {
            int o = idx >> 5, i = idx & 31;
            float acc = 0.f;
#pragma unroll
            for (int bb = 0; bb < NB; bb++) acc += a[bb] * basis2[(bb * NH1 + i) * NH2 + o];
            W2T[r * (NH2 * NH1) + idx] = (__bf16)acc;
        }
    }
}

// ---------------- embed GEMM v2: 64x64 tile, 8 waves, 3 blocks/CU ----------------
// A [64][128] f32 (32KB) + B [64][128] bf16 (16KB) = 48KB LDS -> 24 waves/CU.
// Single-buffered m97 shape; cross-block overlap hides the barrier drain.
// Fused init1 epilogue (out1 = bias1 + h0 @ root1).
__global__ __launch_bounds__(512) void k_gemm(const float* __restrict__ x,
                                              const float* __restrict__ xnorm,
                                              const __bf16* __restrict__ embT,
                                              const float* __restrict__ root1,
                                              const float* __restrict__ bias1,
                                              __bf16* __restrict__ h0b,
                                              float* __restrict__ out1) {
    __shared__ __align__(16) float  As[64 * 128];    // 32,768 B
    __shared__ __align__(16) __bf16 Bs[64 * 128];    // 16,384 B
    int t = threadIdx.x;
    int wv = t >> 6, lane = t & 63;
    int l15 = lane & 15, kg = lane >> 4;
    int rowbase = blockIdx.x * 64;
    int wr = wv >> 1, wc = wv & 1;            // wave -> (row-quad, col-half)
    int half = lane >> 5;                      // A: row within 1KB pair
    int bslot = lane & 31;                     // A: 16B slot within 512B row
    int q16 = lane >> 4;                       // B: row within 1KB quad
    int slot16 = lane & 15;                    // B: 16B slot within 256B row
    int arow_l = wr * 16 + l15;                // A LDS row this lane reads
    int aswz = (arow_l & 7) << 4;
    int n0 = wc * 32 + l15, n1 = n0 + 16;
    int nswz0 = (n0 & 7) << 4, nswz1 = (n1 & 7) << 4;
    const char* asrow  = (const char*)As + arow_l * 512;
    const char* bsrow0 = (const char*)Bs + n0 * 256;
    const char* bsrow1 = (const char*)Bs + n1 * 256;
    f4 acc0 = (f4)0.0f, acc1 = (f4)0.0f;

    for (int c = 0; c < 16; c++) {
        // ---- stage A: 4 gll/wave (rp in [0,32): 2 rows x 512B each = 32KB) ----
#pragma unroll
        for (int i = 0; i < 4; i++) {
            int rp = wv * 4 + i;
            int row = rp * 2 + half;               // [0,64)
            int grow = rowbase + row;
            if (grow >= NN) grow = NN - 1;
            const char* g = (const char*)x + (size_t)grow * (IND * 4) + c * 512
                          + ((bslot * 16) ^ ((row & 7) << 4));
            gll16(g, (char*)As + rp * 1024);
        }
        // ---- stage B: 2 gll/wave (rp in [0,16): 4 rows x 256B each = 16KB) ----
#pragma unroll
        for (int i = 0; i < 2; i++) {
            int rp = wv * 2 + i;
            int row = rp * 4 + q16;                // [0,64)
            const char* g = (const char*)embT + (size_t)row * (IND * 2) + c * 256
                          + ((slot16 * 16) ^ ((row & 7) << 4));
            gll16(g, (char*)Bs + rp * 1024);
        }
        __syncthreads();
        // ---- compute: 8 MFMA per wave ----
#pragma unroll
        for (int kk = 0; kk < 4; kk++) {
            int aoff = ((kk * 128 + kg * 32) ^ aswz);
            float4 lo = *(const float4*)(asrow + aoff);
            float4 hi = *(const float4*)(asrow + (aoff ^ 16));
            bf8 b0 = *(const bf8*)(bsrow0 + ((kk * 64 + kg * 16) ^ nswz0));
            bf8 b1 = *(const bf8*)(bsrow1 + ((kk * 64 + kg * 16) ^ nswz1));
            bf8 a;
            a[0]=(__bf16)lo.x; a[1]=(__bf16)lo.y; a[2]=(__bf16)lo.z; a[3]=(__bf16)lo.w;
            a[4]=(__bf16)hi.x; a[5]=(__bf16)hi.y; a[6]=(__bf16)hi.z; a[7]=(__bf16)hi.w;
            acc0 = __builtin_amdgcn_mfma_f32_16x16x32_bf16(a, b0, acc0, 0, 0, 0);
            acc1 = __builtin_amdgcn_mfma_f32_16x16x32_bf16(a, b1, acc1, 0, 0, 0);
        }
        __syncthreads();
    }
    // ---- epilogue: h0 -> global + LDS, then fused init1 ----
    __bf16* h0s = (__bf16*)As;                 // 64 x 64 bf16 = 8 KB
#pragma unroll
    for (int j = 0; j < 4; j++) {
        int lr = wr * 16 + kg * 4 + j;         // local row
        int r = rowbase + lr;
        float v0 = 0.f, v1 = 0.f;
        if (r < NN) {
            float inv = 1.0f / xnorm[r];
            v0 = acc0[j] * inv;
            v1 = acc1[j] * inv;
        }
        __bf16 b0 = (__bf16)v0, b1 = (__bf16)v1;
        if (r < NN) {
            h0b[(size_t)r * NEMB + n0] = b0;
            h0b[(size_t)r * NEMB + n1] = b1;
        }
        h0s[lr * NEMB + n0] = b0;
        h0s[lr * NEMB + n1] = b1;
    }
    __syncthreads();
    // init1: 512 threads, row = t>>3 (64 rows), cols (t&7)*4..+3
    {
        int row = t >> 3, c0 = (t & 7) * 4;
        int grow = rowbase + row;
        if (grow < NN) {
            const __bf16* hr = h0s + row * NEMB;
            float4 acc = *(const float4*)(bias1 + c0);
#pragma unroll
            for (int k = 0; k < NEMB; k++) {
                float a = (float)hr[k];
                float4 w = *(const float4*)(root1 + k * NH1 + c0);
                acc.x += a * w.x; acc.y += a * w.y;
                acc.z += a * w.z; acc.w += a * w.w;
            }
            *(float4*)(out1 + (size_t)grow * NH1 + c0) = acc;
        }
    }
}

// ---------------- edge layer 1 (r10 verbatim): atomic scatter ----------------
__global__ __launch_bounds__(256) void k_edge1(const int* __restrict__ ei,
                                               const int* __restrict__ et,
                                               const __bf16* __restrict__ h0b,
                                               const __bf16* __restrict__ W1T,
                                               float* __restrict__ out1) {
    int wave = threadIdx.x >> 6, lane = threadIdx.x & 63;
    int l15 = lane & 15, kg = lane >> 4;
    int wid = blockIdx.x * 4 + wave;             // 30000 waves, 32 edges each
    int er0 = wid * 32 + l15, er1 = er0 + 16;
    int et0v = et[er0],  et1v = et[er1];
    int src0 = ei[er0],  src1 = ei[er1];
    int dst0 = ei[EE + er0], dst1 = ei[EE + er1];
    const __bf16* hp0 = h0b + (size_t)src0 * NEMB + kg * 8;
    const __bf16* hp1 = h0b + (size_t)src1 * NEMB + kg * 8;
    bf8 a00 = *(const bf8*)hp0;
    bf8 a01 = *(const bf8*)(hp0 + 32);
    bf8 a10 = *(const bf8*)hp1;
    bf8 a11 = *(const bf8*)(hp1 + 32);
    bf8 zero = bf8_zero();
#pragma unroll
    for (int b = 0; b < 2; b++) {
        int my_et = b ? et1v : et0v;
        int my_dst = b ? dst1 : dst0;
        bf8 a0 = b ? a10 : a00;
        bf8 a1 = b ? a11 : a01;
        f4 c0 = (f4)0.0f, c1 = (f4)0.0f;
        int pos = 0;
        while (pos < 16) {
            int r = __shfl(my_et, pos);
            unsigned long long bl = __ballot(my_et == r);
            unsigned m16 = (unsigned)(bl & 0xFFFFull);
            int run = __builtin_ctz(~(m16 >> pos));
            int end = pos + run;
            const __bf16* wb = W1T + (size_t)r * (NH1 * NEMB) + (size_t)l15 * NEMB + kg * 8;
            bf8 b00 = *(const bf8*)(wb);
            bf8 b01 = *(const bf8*)(wb + 32);
            bf8 b10 = *(const bf8*)(wb + 16 * NEMB);
            bf8 b11 = *(const bf8*)(wb + 16 * NEMB + 32);
            bool use = (l15 >= pos) && (l15 < end);
            bf8 ua0 = use ? a0 : zero;
            bf8 ua1 = use ? a1 : zero;
            c0 = __builtin_amdgcn_mfma_f32_16x16x32_bf16(ua0, b00, c0, 0, 0, 0);
            c0 = __builtin_amdgcn_mfma_f32_16x16x32_bf16(ua1, b01, c0, 0, 0, 0);
            c1 = __builtin_amdgcn_mfma_f32_16x16x32_bf16(ua0, b10, c1, 0, 0, 0);
            c1 = __builtin_amdgcn_mfma_f32_16x16x32_bf16(ua1, b11, c1, 0, 0, 0);
            pos = end;
        }
#pragma unroll
        for (int j = 0; j < 4; j++) {
            int eidx = kg * 4 + j;               // C row = edge index in batch
            int dst = __shfl(my_dst, eidx);
            atomicAdd(out1 + (size_t)dst * NH1 + l15,      c0[j]);
            atomicAdd(out1 + (size_t)dst * NH1 + 16 + l15, c1[j]);
        }
    }
}

// ---------------- mid (r10 verbatim): relu -> h1b AND out = bias2 + h1 @ root2 ----
__global__ __launch_bounds__(256) void k_mid(const float* __restrict__ out1,
                                             const float* __restrict__ root2,
                                             const float* __restrict__ bias2,
                                             __bf16* __restrict__ h1b,
                                             float* __restrict__ out) {
    int t = threadIdx.x;
    int row = blockIdx.x * 16 + (t >> 4);        // 1875 blocks exact
    int col = t & 15;
    const float* orow = out1 + (size_t)row * NH1;
    float h[NH1];
#pragma unroll
    for (int k = 0; k < NH1; k++) h[k] = fmaxf(orow[k], 0.f);
    bf2 hb;
    hb[0] = (__bf16)h[2 * col];
    hb[1] = (__bf16)h[2 * col + 1];
    *(bf2*)(h1b + (size_t)row * NH1 + 2 * col) = hb;
    float acc = bias2[col];
#pragma unroll
    for (int k = 0; k < NH1; k++) acc += h[k] * root2[k * NH2 + col];
    out[(size_t)row * NH2 + col] = acc;
}

// ---------------- edge layer 2 (r10 verbatim): atomic scatter ----------------
__global__ __launch_bounds__(256) void k_edge2(const int* __restrict__ ei,
                                               const int* __restrict__ et,
                                               const __bf16* __restrict__ h1b,
                                               const __bf16* __restrict__ W2T,
                                               float* __restrict__ out) {
    int wave = threadIdx.x >> 6, lane = threadIdx.x & 63;
    int l15 = lane & 15, kg = lane >> 4;
    int wid = blockIdx.x * 4 + wave;
    int er0 = wid * 32 + l15, er1 = er0 + 16;
    int et0v = et[er0],  et1v = et[er1];
    int src0 = ei[er0],  src1 = ei[er1];
    int dst0 = ei[EE + er0], dst1 = ei[EE + er1];
    bf8 ab0 = *(const bf8*)(h1b + (size_t)src0 * NH1 + kg * 8);
    bf8 ab1 = *(const bf8*)(h1b + (size_t)src1 * NH1 + kg * 8);
    bf8 zero = bf8_zero();
#pragma unroll
    for (int b = 0; b < 2; b++) {
        int my_et = b ? et1v : et0v;
        int my_dst = b ? dst1 : dst0;
        bf8 a = b ? ab1 : ab0;
        f4 c = (f4)0.0f;
        int pos = 0;
        while (pos < 16) {
            int r = __shfl(my_et, pos);
            unsigned long long bl = __ballot(my_et == r);
            unsigned m16 = (unsigned)(bl & 0xFFFFull);
            int run = __builtin_ctz(~(m16 >> pos));
            int end = pos + run;
            bf8 bb = *(const bf8*)(W2T + (size_t)r * (NH2 * NH1) + (size_t)l15 * NH1 + kg * 8);
            bool use = (l15 >= pos) && (l15 < end);
            c = __builtin_amdgcn_mfma_f32_16x16x32_bf16(use ? a : zero, bb, c, 0, 0, 0);
            pos = end;
        }
#pragma unroll
        for (int j = 0; j < 4; j++) {
            int eidx = kg * 4 + j;
            int dst = __shfl(my_dst, eidx);
            atomicAdd(out + (size_t)dst * NH2 + l15, c[j]);
        }
    }
}

// ---------------- relu2 (in place on d_out) ----------------
__global__ __launch_bounds__(256) void k_relu2(float* __restrict__ o) {
    int i = blockIdx.x * 256 + threadIdx.x;
    if (i >= NN * NH2 / 4) return;
    float4 v = ((float4*)o)[i];
    v.x = fmaxf(v.x, 0.f); v.y = fmaxf(v.y, 0.f);
    v.z = fmaxf(v.z, 0.f); v.w = fmaxf(v.w, 0.f);
    ((float4*)o)[i] = v;
}

// ---------------- launch ----------------
extern "C" void kernel_launch(void* const* d_in, const int* in_sizes, int n_in,
                              void* d_out, int out_size, void* d_ws, size_t ws_size,
                              hipStream_t stream) {
    const float* x      = (const float*)d_in[0];
    const int*   ei     = (const int*)d_in[1];
    const int*   et     = (const int*)d_in[2];
    const float* xnorm  = (const float*)d_in[4];
    const float* embed  = (const float*)d_in[5];
    const float* basis1 = (const float*)d_in[6];
    const float* att1   = (const float*)d_in[7];
    const float* root1  = (const float*)d_in[8];
    const float* bias1  = (const float*)d_in[9];
    const float* basis2 = (const float*)d_in[10];
    const float* att2   = (const float*)d_in[11];
    const float* root2  = (const float*)d_in[12];
    const float* bias2  = (const float*)d_in[13];
    float* out = (float*)d_out;

    char* ws = (char*)d_ws;
    __bf16* embT = (__bf16*)(ws + 0);              //   262,144
    __bf16* W1T  = (__bf16*)(ws + 262144);         //   262,144
    __bf16* W2T  = (__bf16*)(ws + 524288);         //    65,536
    __bf16* h0b  = (__bf16*)(ws + 589824);         // 3,840,000
    float*  out1 = (float*) (ws + 4429824);        // 3,840,000
    __bf16* h1b  = (__bf16*)(ws + 8269824);        // 1,920,000  (end ~10.2 MB)

    k_prep <<<640,  256, 0, stream>>>(embed, basis1, att1, basis2, att2, embT, W1T, W2T);
    k_gemm <<<469,  512, 0, stream>>>(x, xnorm, embT, root1, bias1, h0b, out1);
    k_edge1<<<7500, 256, 0, stream>>>(ei, et, h0b, W1T, out1);
    k_mid  <<<1875, 256, 0, stream>>>(out1, root2, bias2, h1b, out);
    k_edge2<<<7500, 256, 0, stream>>>(ei, et, h1b, W2T, out);
    k_relu2<<<469,  256, 0, stream>>>(out);
}

// Round 19
// 227.385 us; speedup vs baseline: 3.3767x; 1.0109x over previous
//
#include <hip/hip_runtime.h>
#include <hip/hip_bf16.h>

#define NN   30000
#define EE   960000
#define IND  2048
#define NEMB 64
#define NH1  32
#define NH2  16
#define NET  64
#define NB   16

typedef __bf16 bf8 __attribute__((ext_vector_type(8)));
typedef __bf16 bf4 __attribute__((ext_vector_type(4)));
typedef __bf16 bf2 __attribute__((ext_vector_type(2)));
typedef float  f4  __attribute__((ext_vector_type(4)));

#define AS3 __attribute__((address_space(3)))
#define AS1 __attribute__((address_space(1)))

__device__ __forceinline__ void gll16(const void* g, void* l) {
    __builtin_amdgcn_global_load_lds((const AS1 unsigned int*)g,
                                     (AS3 unsigned int*)l, 16, 0, 0);
}

__device__ __forceinline__ bf8 bf8_zero() {
    bf8 z;
#pragma unroll
    for (int i = 0; i < 8; i++) z[i] = (__bf16)0.0f;
    return z;
}

// ---------------- prep: embT + W1T + W2T (grid-split, r10 verbatim) ----------------
__global__ __launch_bounds__(256) void k_prep(const float* __restrict__ embed,
                                              const float* __restrict__ basis1,
                                              const float* __restrict__ att1,
                                              const float* __restrict__ basis2,
                                              const float* __restrict__ att2,
                                              __bf16* __restrict__ embT,
                                              __bf16* __restrict__ W1T,
                                              __bf16* __restrict__ W2T) {
    int b = blockIdx.x;
    if (b < 512) {
        int idx = b * 256 + threadIdx.x;        // embT[n][k] = embed[k][n]
        int n = idx >> 11, k = idx & 2047;
        embT[idx] = (__bf16)embed[k * NEMB + n];
    } else if (b < 576) {
        int r = b - 512;
        __shared__ float a[NB];
        if (threadIdx.x < NB) a[threadIdx.x] = att1[r * NB + threadIdx.x];
        __syncthreads();
        for (int idx = threadIdx.x; idx < NH1 * NEMB; idx += 256) {
            int o = idx >> 6, i = idx & 63;
            float acc = 0.f;
#pragma unroll
            for (int bb = 0; bb < NB; bb++) acc += a[bb] * basis1[(bb * NEMB + i) * NH1 + o];
            W1T[r * (NH1 * NEMB) + idx] = (__bf16)acc;
        }
    } else {
        int r = b - 576;
        __shared__ float a[NB];
        if (threadIdx.x < NB) a[threadIdx.x] = att2[r * NB + threadIdx.x];
        __syncthreads();
        for (int idx = threadIdx.x; idx < NH2 * NH1; idx += 256) {
            int o = idx >> 5, i = idx & 31;
            float acc = 0.f;
#pragma unroll
            for (int bb = 0; bb < NB; bb++) acc += a[bb] * basis2[(bb * NH1 + i) * NH2 + o];
            W2T[r * (NH2 * NH1) + idx] = (__bf16)acc;
        }
    }
}

// ---------------- embed GEMM v3: 64x64 tile, BK=64, 24 KB LDS -> 32 waves/CU ------
// A [64][64] f32 (16KB) + B [64][64] bf16 (8KB); 4 blocks/CU x 8 waves.
// Fused init1 epilogue (out1 = bias1 + h0 @ root1).
__global__ __launch_bounds__(512) void k_gemm(const float* __restrict__ x,
                                              const float* __restrict__ xnorm,
                                              const __bf16* __restrict__ embT,
                                              const float* __restrict__ root1,
                                              const float* __restrict__ bias1,
                                              __bf16* __restrict__ h0b,
                                              float* __restrict__ out1) {
    __shared__ __align__(16) float  As[64 * 64];     // 16,384 B
    __shared__ __align__(16) __bf16 Bs[64 * 64];     //  8,192 B
    int t = threadIdx.x;
    int wv = t >> 6, lane = t & 63;
    int l15 = lane & 15, kg = lane >> 4;
    int rowbase = blockIdx.x * 64;
    int wr = wv >> 1, wc = wv & 1;            // wave -> (row-quad, col-half)
    int q16 = lane >> 4, slot16 = lane & 15;  // A: 4 rows x 256B per KB
    int r8i = lane >> 3, slot8 = lane & 7;    // B: 8 rows x 128B per KB
    int arow_l = wr * 16 + l15;               // A LDS row this lane reads
    int aswz = (arow_l & 7) << 4;
    int n0 = wc * 32 + l15, n1 = n0 + 16;
    int nswz0 = (n0 & 7) << 4, nswz1 = (n1 & 7) << 4;
    const char* asrow  = (const char*)As + arow_l * 256;
    const char* bsrow0 = (const char*)Bs + n0 * 128;
    const char* bsrow1 = (const char*)Bs + n1 * 128;
    f4 acc0 = (f4)0.0f, acc1 = (f4)0.0f;

    for (int c = 0; c < 32; c++) {
        // ---- stage A: 2 gll/wave (rp in [0,16): 4 rows x 256B each = 16KB) ----
#pragma unroll
        for (int i = 0; i < 2; i++) {
            int rp = wv * 2 + i;
            int row = rp * 4 + q16;                // [0,64)
            int grow = rowbase + row;
            if (grow >= NN) grow = NN - 1;
            const char* g = (const char*)x + (size_t)grow * (IND * 4) + c * 256
                          + ((slot16 * 16) ^ ((row & 7) << 4));
            gll16(g, (char*)As + rp * 1024);
        }
        // ---- stage B: 1 gll/wave (rp in [0,8): 8 rows x 128B each = 8KB) ----
        {
            int rp = wv;
            int row = rp * 8 + r8i;                // [0,64)
            const char* g = (const char*)embT + (size_t)row * (IND * 2) + c * 128
                          + ((slot8 * 16) ^ ((row & 7) << 4));
            gll16(g, (char*)Bs + rp * 1024);
        }
        __syncthreads();
        // ---- compute: 4 MFMA per wave ----
#pragma unroll
        for (int kk = 0; kk < 2; kk++) {
            int aoff = ((kk * 128 + kg * 32) ^ aswz);
            float4 lo = *(const float4*)(asrow + aoff);
            float4 hi = *(const float4*)(asrow + (aoff ^ 16));
            bf8 b0 = *(const bf8*)(bsrow0 + ((kk * 64 + kg * 16) ^ nswz0));
            bf8 b1 = *(const bf8*)(bsrow1 + ((kk * 64 + kg * 16) ^ nswz1));
            bf8 a;
            a[0]=(__bf16)lo.x; a[1]=(__bf16)lo.y; a[2]=(__bf16)lo.z; a[3]=(__bf16)lo.w;
            a[4]=(__bf16)hi.x; a[5]=(__bf16)hi.y; a[6]=(__bf16)hi.z; a[7]=(__bf16)hi.w;
            acc0 = __builtin_amdgcn_mfma_f32_16x16x32_bf16(a, b0, acc0, 0, 0, 0);
            acc1 = __builtin_amdgcn_mfma_f32_16x16x32_bf16(a, b1, acc1, 0, 0, 0);
        }
        __syncthreads();
    }
    // ---- epilogue: h0 -> global + LDS, then fused init1 ----
    __bf16* h0s = (__bf16*)As;                 // 64 x 64 bf16 = 8 KB (fits in As)
#pragma unroll
    for (int j = 0; j < 4; j++) {
        int lr = wr * 16 + kg * 4 + j;         // local row
        int r = rowbase + lr;
        float v0 = 0.f, v1 = 0.f;
        if (r < NN) {
            float inv = 1.0f / xnorm[r];
            v0 = acc0[j] * inv;
            v1 = acc1[j] * inv;
        }
        __bf16 b0 = (__bf16)v0, b1 = (__bf16)v1;
        if (r < NN) {
            h0b[(size_t)r * NEMB + n0] = b0;
            h0b[(size_t)r * NEMB + n1] = b1;
        }
        h0s[lr * NEMB + n0] = b0;
        h0s[lr * NEMB + n1] = b1;
    }
    __syncthreads();
    // init1: 512 threads, row = t>>3 (64 rows), cols (t&7)*4..+3
    {
        int row = t >> 3, c0 = (t & 7) * 4;
        int grow = rowbase + row;
        if (grow < NN) {
            const __bf16* hr = h0s + row * NEMB;
            float4 acc = *(const float4*)(bias1 + c0);
#pragma unroll
            for (int k = 0; k < NEMB; k++) {
                float a = (float)hr[k];
                float4 w = *(const float4*)(root1 + k * NH1 + c0);
                acc.x += a * w.x; acc.y += a * w.y;
                acc.z += a * w.z; acc.w += a * w.w;
            }
            *(float4*)(out1 + (size_t)grow * NH1 + c0) = acc;
        }
    }
}

// ---------------- edge layer 1 (r10 verbatim): atomic scatter ----------------
__global__ __launch_bounds__(256) void k_edge1(const int* __restrict__ ei,
                                               const int* __restrict__ et,
                                               const __bf16* __restrict__ h0b,
                                               const __bf16* __restrict__ W1T,
                                               float* __restrict__ out1) {
    int wave = threadIdx.x >> 6, lane = threadIdx.x & 63;
    int l15 = lane & 15, kg = lane >> 4;
    int wid = blockIdx.x * 4 + wave;             // 30000 waves, 32 edges each
    int er0 = wid * 32 + l15, er1 = er0 + 16;
    int et0v = et[er0],  et1v = et[er1];
    int src0 = ei[er0],  src1 = ei[er1];
    int dst0 = ei[EE + er0], dst1 = ei[EE + er1];
    const __bf16* hp0 = h0b + (size_t)src0 * NEMB + kg * 8;
    const __bf16* hp1 = h0b + (size_t)src1 * NEMB + kg * 8;
    bf8 a00 = *(const bf8*)hp0;
    bf8 a01 = *(const bf8*)(hp0 + 32);
    bf8 a10 = *(const bf8*)hp1;
    bf8 a11 = *(const bf8*)(hp1 + 32);
    bf8 zero = bf8_zero();
#pragma unroll
    for (int b = 0; b < 2; b++) {
        int my_et = b ? et1v : et0v;
        int my_dst = b ? dst1 : dst0;
        bf8 a0 = b ? a10 : a00;
        bf8 a1 = b ? a11 : a01;
        f4 c0 = (f4)0.0f, c1 = (f4)0.0f;
        int pos = 0;
        while (pos < 16) {
            int r = __shfl(my_et, pos);
            unsigned long long bl = __ballot(my_et == r);
            unsigned m16 = (unsigned)(bl & 0xFFFFull);
            int run = __builtin_ctz(~(m16 >> pos));
            int end = pos + run;
            const __bf16* wb = W1T + (size_t)r * (NH1 * NEMB) + (size_t)l15 * NEMB + kg * 8;
            bf8 b00 = *(const bf8*)(wb);
            bf8 b01 = *(const bf8*)(wb + 32);
            bf8 b10 = *(const bf8*)(wb + 16 * NEMB);
            bf8 b11 = *(const bf8*)(wb + 16 * NEMB + 32);
            bool use = (l15 >= pos) && (l15 < end);
            bf8 ua0 = use ? a0 : zero;
            bf8 ua1 = use ? a1 : zero;
            c0 = __builtin_amdgcn_mfma_f32_16x16x32_bf16(ua0, b00, c0, 0, 0, 0);
            c0 = __builtin_amdgcn_mfma_f32_16x16x32_bf16(ua1, b01, c0, 0, 0, 0);
            c1 = __builtin_amdgcn_mfma_f32_16x16x32_bf16(ua0, b10, c1, 0, 0, 0);
            c1 = __builtin_amdgcn_mfma_f32_16x16x32_bf16(ua1, b11, c1, 0, 0, 0);
            pos = end;
        }
#pragma unroll
        for (int j = 0; j < 4; j++) {
            int eidx = kg * 4 + j;               // C row = edge index in batch
            int dst = __shfl(my_dst, eidx);
            atomicAdd(out1 + (size_t)dst * NH1 + l15,      c0[j]);
            atomicAdd(out1 + (size_t)dst * NH1 + 16 + l15, c1[j]);
        }
    }
}

// ---------------- mid (r10 verbatim): relu -> h1b AND out = bias2 + h1 @ root2 ----
__global__ __launch_bounds__(256) void k_mid(const float* __restrict__ out1,
                                             const float* __restrict__ root2,
                                             const float* __restrict__ bias2,
                                             __bf16* __restrict__ h1b,
                                             float* __restrict__ out) {
    int t = threadIdx.x;
    int row = blockIdx.x * 16 + (t >> 4);        // 1875 blocks exact
    int col = t & 15;
    const float* orow = out1 + (size_t)row * NH1;
    float h[NH1];
#pragma unroll
    for (int k = 0; k < NH1; k++) h[k] = fmaxf(orow[k], 0.f);
    bf2 hb;
    hb[0] = (__bf16)h[2 * col];
    hb[1] = (__bf16)h[2 * col + 1];
    *(bf2*)(h1b + (size_t)row * NH1 + 2 * col) = hb;
    float acc = bias2[col];
#pragma unroll
    for (int k = 0; k < NH1; k++) acc += h[k] * root2[k * NH2 + col];
    out[(size_t)row * NH2 + col] = acc;
}

// ---------------- edge layer 2 (r10 verbatim): atomic scatter ----------------
__global__ __launch_bounds__(256) void k_edge2(const int* __restrict__ ei,
                                               const int* __restrict__ et,
                                               const __bf16* __restrict__ h1b,
                                               const __bf16* __restrict__ W2T,
                                               float* __restrict__ out) {
    int wave = threadIdx.x >> 6, lane = threadIdx.x & 63;
    int l15 = lane & 15, kg = lane >> 4;
    int wid = blockIdx.x * 4 + wave;
    int er0 = wid * 32 + l15, er1 = er0 + 16;
    int et0v = et[er0],  et1v = et[er1];
    int src0 = ei[er0],  src1 = ei[er1];
    int dst0 = ei[EE + er0], dst1 = ei[EE + er1];
    bf8 ab0 = *(const bf8*)(h1b + (size_t)src0 * NH1 + kg * 8);
    bf8 ab1 = *(const bf8*)(h1b + (size_t)src1 * NH1 + kg * 8);
    bf8 zero = bf8_zero();
#pragma unroll
    for (int b = 0; b < 2; b++) {
        int my_et = b ? et1v : et0v;
        int my_dst = b ? dst1 : dst0;
        bf8 a = b ? ab1 : ab0;
        f4 c = (f4)0.0f;
        int pos = 0;
        while (pos < 16) {
            int r = __shfl(my_et, pos);
            unsigned long long bl = __ballot(my_et == r);
            unsigned m16 = (unsigned)(bl & 0xFFFFull);
            int run = __builtin_ctz(~(m16 >> pos));
            int end = pos + run;
            bf8 bb = *(const bf8*)(W2T + (size_t)r * (NH2 * NH1) + (size_t)l15 * NH1 + kg * 8);
            bool use = (l15 >= pos) && (l15 < end);
            c = __builtin_amdgcn_mfma_f32_16x16x32_bf16(use ? a : zero, bb, c, 0, 0, 0);
            pos = end;
        }
#pragma unroll
        for (int j = 0; j < 4; j++) {
            int eidx = kg * 4 + j;
            int dst = __shfl(my_dst, eidx);
            atomicAdd(out + (size_t)dst * NH2 + l15, c[j]);
        }
    }
}

// ---------------- relu2 (in place on d_out) ----------------
__global__ __launch_bounds__(256) void k_relu2(float* __restrict__ o) {
    int i = blockIdx.x * 256 + threadIdx.x;
    if (i >= NN * NH2 / 4) return;
    float4 v = ((float4*)o)[i];
    v.x = fmaxf(v.x, 0.f); v.y = fmaxf(v.y, 0.f);
    v.z = fmaxf(v.z, 0.f); v.w = fmaxf(v.w, 0.f);
    ((float4*)o)[i] = v;
}

// ---------------- launch ----------------
extern "C" void kernel_launch(void* const* d_in, const int* in_sizes, int n_in,
                              void* d_out, int out_size, void* d_ws, size_t ws_size,
                              hipStream_t stream) {
    const float* x      = (const float*)d_in[0];
    const int*   ei     = (const int*)d_in[1];
    const int*   et     = (const int*)d_in[2];
    const float* xnorm  = (const float*)d_in[4];
    const float* embed  = (const float*)d_in[5];
    const float* basis1 = (const float*)d_in[6];
    const float* att1   = (const float*)d_in[7];
    const float* root1  = (const float*)d_in[8];
    const float* bias1  = (const float*)d_in[9];
    const float* basis2 = (const float*)d_in[10];
    const float* att2   = (const float*)d_in[11];
    const float* root2  = (const float*)d_in[12];
    const float* bias2  = (const float*)d_in[13];
    float* out = (float*)d_out;

    char* ws = (char*)d_ws;
    __bf16* embT = (__bf16*)(ws + 0);              //   262,144
    __bf16* W1T  = (__bf16*)(ws + 262144);         //   262,144
    __bf16* W2T  = (__bf16*)(ws + 524288);         //    65,536
    __bf16* h0b  = (__bf16*)(ws + 589824);         // 3,840,000
    float*  out1 = (float*) (ws + 4429824);        // 3,840,000
    __bf16* h1b  = (__bf16*)(ws + 8269824);        // 1,920,000  (end ~10.2 MB)

    k_prep <<<640,  256, 0, stream>>>(embed, basis1, att1, basis2, att2, embT, W1T, W2T);
    k_gemm <<<469,  512, 0, stream>>>(x, xnorm, embT, root1, bias1, h0b, out1);
    k_edge1<<<7500, 256, 0, stream>>>(ei, et, h0b, W1T, out1);
    k_mid  <<<1875, 256, 0, stream>>>(out1, root2, bias2, h1b, out);
    k_edge2<<<7500, 256, 0, stream>>>(ei, et, h1b, W2T, out);
    k_relu2<<<469,  256, 0, stream>>>(out);
}